// Round 3
// baseline (751.633 us; speedup 1.0000x reference)
//
#include <hip/hip_runtime.h>
#include <hip/hip_bf16.h>

#define N_NODES 50000
#define N_EDGES 500000
#define F_DIM   128
#define N_REL   8
#define N_LAYERS 2
#define NEG_SLOPE 0.2f

#define NBLK_N ((N_NODES + 255) / 256)   // 196 blocks over nodes

typedef short bf16x8 __attribute__((ext_vector_type(8)));
typedef float f32x4  __attribute__((ext_vector_type(4)));

// ---------------- helpers ----------------

__device__ inline short bfbits(float x) {
    __hip_bfloat16 h = __float2bfloat16(x);
    return *reinterpret_cast<short*>(&h);
}
__device__ inline float bf2f(short s) {
    unsigned u = ((unsigned)(unsigned short)s) << 16;
    return __uint_as_float(u);
}
__device__ inline float lrelu(float l) { return (l > 0.f) ? l : NEG_SLOPE * l; }

// ---------------- W prep: W[l,r,f,g] fp32 -> Wh/Wl[l,r,g,f] bf16 split -------
// one block per (l,r) matrix; two 64-f-row passes through LDS.
__global__ __launch_bounds__(256) void prep_w(const float* __restrict__ W,
                                              short* __restrict__ Wh,
                                              short* __restrict__ Wl) {
    __shared__ float tile[64][F_DIM + 1];
    const int mat = blockIdx.x;                      // l*N_REL + r
    const float* src = W + (size_t)mat * F_DIM * F_DIM;
    const int t = threadIdx.x;
    for (int hf = 0; hf < 2; ++hf) {
        // stage rows f = hf*64 .. +63 (64 x 128 fp32 = 2048 float4)
#pragma unroll
        for (int i = 0; i < 8; ++i) {
            int idx = t + i * 256;
            int f = idx >> 5, c4 = idx & 31;
            float4 v = *(const float4*)(src + (size_t)(hf * 64 + f) * F_DIM + c4 * 4);
            *(float4*)&tile[f][c4 * 4] = v;
        }
        __syncthreads();
        // output: g = t>>1 (128 g), f-sub = (t&1)*32..+31
        int g = t >> 1, fs = (t & 1) * 32;
        for (int c = 0; c < 4; ++c) {
            short th[8], tl[8];
#pragma unroll
            for (int j = 0; j < 8; ++j) {
                float x = tile[fs + c * 8 + j][g];
                short hb = bfbits(x);
                th[j] = hb;
                tl[j] = bfbits(x - bf2f(hb));
            }
            size_t o = ((size_t)mat * F_DIM + g) * F_DIM + hf * 64 + fs + c * 8;
            *(uint4*)(Wh + o) = *(const uint4*)th;
            *(uint4*)(Wl + o) = *(const uint4*)tl;
        }
        __syncthreads();
    }
}

// ---------------- MFMA GEMM (+fused q/k dots) ----------------
// block: 64 node-rows, 4 waves (16 rows each), all 8 relations.
// xw[r,n,g] fp32; a_q[r,n], a_k[r,n].
#define BM 64
__global__ __launch_bounds__(256) void gemm_xw(const float* __restrict__ H,
                                               const short* __restrict__ Wh,
                                               const short* __restrict__ Wl,
                                               const float* __restrict__ qv_g,
                                               const float* __restrict__ kv_g,
                                               float* __restrict__ xw,
                                               float* __restrict__ a_q,
                                               float* __restrict__ a_k) {
    __shared__ float As[BM][F_DIM + 4];
    const int m0 = blockIdx.x * BM;
    const int tid = threadIdx.x;
    const int lane = tid & 63, w = tid >> 6;

    // stage H tile fp32 (64 x 128 = 2048 float4, 8/thread), coalesced
#pragma unroll
    for (int i = 0; i < 8; ++i) {
        int idx = tid + i * 256;
        int row = idx >> 5, c4 = idx & 31;
        int gm = m0 + row;
        float4 v = make_float4(0.f, 0.f, 0.f, 0.f);
        if (gm < N_NODES) v = *(const float4*)(H + (size_t)gm * F_DIM + c4 * 4);
        *(float4*)&As[row][c4 * 4] = v;
    }
    __syncthreads();

    const int q = lane >> 4, ln = lane & 15;
    const int row_l = w * 16 + ln;

    // A fragments (split hi/lo), built once, reused for all 8 relations.
    // layout: A[m = lane&15][k = q*8 + j], k-step ks covers k = ks*32..+31
    bf16x8 Ah[4], Al[4];
#pragma unroll
    for (int ks = 0; ks < 4; ++ks) {
        float av[8];
        *(float4*)(av)     = *(const float4*)&As[row_l][ks * 32 + q * 8];
        *(float4*)(av + 4) = *(const float4*)&As[row_l][ks * 32 + q * 8 + 4];
        bf16x8 h, l;
#pragma unroll
        for (int j = 0; j < 8; ++j) {
            short hb = bfbits(av[j]);
            h[j] = hb;
            l[j] = bfbits(av[j] - bf2f(hb));
        }
        Ah[ks] = h; Al[ks] = l;
    }

    // q/k attention vector elements for this lane's columns
    float qvl[8], kvl[8];
#pragma unroll
    for (int nf = 0; nf < 8; ++nf) {
        qvl[nf] = qv_g[nf * 16 + ln];
        kvl[nf] = kv_g[nf * 16 + ln];
    }

    const int rowg = m0 + w * 16 + q * 4;   // base of this lane's 4 C-rows

    for (int r = 0; r < N_REL; ++r) {
        f32x4 acc[8];
#pragma unroll
        for (int nf = 0; nf < 8; ++nf) acc[nf] = (f32x4)(0.f);
        const short* wh = Wh + (size_t)r * F_DIM * F_DIM;
        const short* wl = Wl + (size_t)r * F_DIM * F_DIM;
#pragma unroll
        for (int ks = 0; ks < 4; ++ks) {
#pragma unroll
            for (int nf = 0; nf < 8; ++nf) {
                size_t bo = (size_t)(nf * 16 + ln) * F_DIM + ks * 32 + q * 8;
                bf16x8 Bh = *(const bf16x8*)(wh + bo);
                bf16x8 Bl = *(const bf16x8*)(wl + bo);
                acc[nf] = __builtin_amdgcn_mfma_f32_16x16x32_bf16(Ah[ks], Bh, acc[nf], 0, 0, 0);
                acc[nf] = __builtin_amdgcn_mfma_f32_16x16x32_bf16(Ah[ks], Bl, acc[nf], 0, 0, 0);
                acc[nf] = __builtin_amdgcn_mfma_f32_16x16x32_bf16(Al[ks], Bh, acc[nf], 0, 0, 0);
            }
        }
        // epilogue: C store (col = nf*16+ln, row = rowg+r4) + fused q/k dots
        float pq[4] = {0, 0, 0, 0}, pk[4] = {0, 0, 0, 0};
#pragma unroll
        for (int nf = 0; nf < 8; ++nf) {
#pragma unroll
            for (int r4 = 0; r4 < 4; ++r4) {
                int row = rowg + r4;
                if (row < N_NODES)
                    xw[((size_t)r * N_NODES + row) * F_DIM + nf * 16 + ln] = acc[nf][r4];
                pq[r4] = fmaf(acc[nf][r4], qvl[nf], pq[r4]);
                pk[r4] = fmaf(acc[nf][r4], kvl[nf], pk[r4]);
            }
        }
#pragma unroll
        for (int r4 = 0; r4 < 4; ++r4) {
#pragma unroll
            for (int m = 1; m <= 8; m <<= 1) {
                pq[r4] += __shfl_xor(pq[r4], m);
                pk[r4] += __shfl_xor(pk[r4], m);
            }
            int row = rowg + r4;
            if (ln == 0 && row < N_NODES) {
                a_q[(size_t)r * N_NODES + row] = pq[r4];
                a_k[(size_t)r * N_NODES + row] = pk[r4];
            }
        }
    }
}

// ---------------- CSR build ----------------

__global__ __launch_bounds__(256) void count_kernel(const int* __restrict__ dstp,
                                                    int* __restrict__ cnt) {
    int e = blockIdx.x * 256 + threadIdx.x;
    if (e < N_EDGES) atomicAdd(cnt + dstp[e], 1);
}

__global__ __launch_bounds__(256) void block_sum_kernel(const int* __restrict__ cnt,
                                                        int* __restrict__ partial) {
    __shared__ int s[256];
    int idx = blockIdx.x * 256 + threadIdx.x;
    int v = (idx < N_NODES) ? cnt[idx] : 0;
    s[threadIdx.x] = v;
    __syncthreads();
    for (int off = 128; off > 0; off >>= 1) {
        if (threadIdx.x < off) s[threadIdx.x] += s[threadIdx.x + off];
        __syncthreads();
    }
    if (threadIdx.x == 0) partial[blockIdx.x] = s[0];
}

__global__ __launch_bounds__(256) void scan_partials_kernel(int* __restrict__ partial,
                                                            int* __restrict__ row_ptr) {
    __shared__ int s[256];
    int t = threadIdx.x;
    int v = (t < NBLK_N) ? partial[t] : 0;
    s[t] = v;
    __syncthreads();
#pragma unroll
    for (int off = 1; off < 256; off <<= 1) {
        int x = (t >= off) ? s[t - off] : 0;
        __syncthreads();
        s[t] += x;
        __syncthreads();
    }
    if (t < NBLK_N) partial[t] = s[t] - v;
    if (t == 0) row_ptr[N_NODES] = N_EDGES;
}

__global__ __launch_bounds__(256) void scan_block_kernel(const int* __restrict__ cnt,
                                                         const int* __restrict__ partial,
                                                         int* __restrict__ row_ptr) {
    __shared__ int s[256];
    int t = threadIdx.x;
    int idx = blockIdx.x * 256 + t;
    int v = (idx < N_NODES) ? cnt[idx] : 0;
    s[t] = v;
    __syncthreads();
#pragma unroll
    for (int off = 1; off < 256; off <<= 1) {
        int x = (t >= off) ? s[t - off] : 0;
        __syncthreads();
        s[t] += x;
        __syncthreads();
    }
    if (idx < N_NODES) row_ptr[idx] = partial[blockIdx.x] + s[t] - v;
}

__global__ __launch_bounds__(256) void scatter_kernel(const int* __restrict__ srcp,
                                                      const int* __restrict__ dstp,
                                                      const int* __restrict__ etp,
                                                      const int* __restrict__ row_ptr,
                                                      int* __restrict__ cursor,
                                                      unsigned* __restrict__ sorted) {
    int e = blockIdx.x * 256 + threadIdx.x;
    if (e >= N_EDGES) return;
    int d = dstp[e];
    int pos = atomicAdd(cursor + d, 1);
    sorted[row_ptr[d] + pos] = (unsigned)srcp[e] | ((unsigned)etp[e] << 16);
}

// ---------------- fused softmax + aggregate + bias + relu ----------------
__global__ __launch_bounds__(256) void agg_fused(const float* __restrict__ xw,
                                                 const float* __restrict__ a_q,
                                                 const float* __restrict__ a_k,
                                                 const int* __restrict__ row_ptr,
                                                 const unsigned* __restrict__ sorted,
                                                 const float* __restrict__ bias,
                                                 float* __restrict__ out) {
    const int lane = threadIdx.x & 63;
    const int wave = threadIdx.x >> 6;
    const int d = blockIdx.x * 4 + wave;
    if (d >= N_NODES) return;
    const int beg = row_ptr[d], end = row_ptr[d + 1];
    const int cnt = end - beg;

    float2 acc = *(const float2*)(bias + lane * 2);

    if (cnt <= 64) {
        // one edge per lane, softmax fully in registers
        unsigned p = 0;
        float l = -3.4e38f;
        if (lane < cnt) {
            p = sorted[beg + lane];
            int s = p & 0xffff, t = p >> 16;
            l = lrelu(a_q[t * N_NODES + d] + a_k[t * N_NODES + s]);
        }
        float m = l;
#pragma unroll
        for (int off = 32; off > 0; off >>= 1) m = fmaxf(m, __shfl_xor(m, off));
        float ex = (lane < cnt) ? __expf(l - m) : 0.f;
        float dsum = ex;
#pragma unroll
        for (int off = 32; off > 0; off >>= 1) dsum += __shfl_xor(dsum, off);
        float alpha = ex / (dsum + 1e-16f);

        int i = 0;
        for (; i + 4 <= cnt; i += 4) {
            unsigned p0 = __shfl(p, i), p1 = __shfl(p, i + 1);
            unsigned p2 = __shfl(p, i + 2), p3 = __shfl(p, i + 3);
            float a0 = __shfl(alpha, i), a1 = __shfl(alpha, i + 1);
            float a2 = __shfl(alpha, i + 2), a3 = __shfl(alpha, i + 3);
            float2 v0 = *(const float2*)(xw + (((size_t)(p0 >> 16)) * N_NODES + (p0 & 0xffff)) * F_DIM + lane * 2);
            float2 v1 = *(const float2*)(xw + (((size_t)(p1 >> 16)) * N_NODES + (p1 & 0xffff)) * F_DIM + lane * 2);
            float2 v2 = *(const float2*)(xw + (((size_t)(p2 >> 16)) * N_NODES + (p2 & 0xffff)) * F_DIM + lane * 2);
            float2 v3 = *(const float2*)(xw + (((size_t)(p3 >> 16)) * N_NODES + (p3 & 0xffff)) * F_DIM + lane * 2);
            acc.x = fmaf(a0, v0.x, acc.x); acc.y = fmaf(a0, v0.y, acc.y);
            acc.x = fmaf(a1, v1.x, acc.x); acc.y = fmaf(a1, v1.y, acc.y);
            acc.x = fmaf(a2, v2.x, acc.x); acc.y = fmaf(a2, v2.y, acc.y);
            acc.x = fmaf(a3, v3.x, acc.x); acc.y = fmaf(a3, v3.y, acc.y);
        }
        for (; i < cnt; ++i) {
            unsigned pi = __shfl(p, i);
            float ai = __shfl(alpha, i);
            float2 v = *(const float2*)(xw + (((size_t)(pi >> 16)) * N_NODES + (pi & 0xffff)) * F_DIM + lane * 2);
            acc.x = fmaf(ai, v.x, acc.x);
            acc.y = fmaf(ai, v.y, acc.y);
        }
    } else {
        // rare high-degree fallback: 3-phase strided
        float m = -3.4e38f;
        for (int i = beg + lane; i < end; i += 64) {
            unsigned p = sorted[i];
            int s = p & 0xffff, t = p >> 16;
            m = fmaxf(m, lrelu(a_q[t * N_NODES + d] + a_k[t * N_NODES + s]));
        }
#pragma unroll
        for (int off = 32; off > 0; off >>= 1) m = fmaxf(m, __shfl_xor(m, off));
        float dsum = 0.f;
        for (int i = beg + lane; i < end; i += 64) {
            unsigned p = sorted[i];
            int s = p & 0xffff, t = p >> 16;
            dsum += __expf(lrelu(a_q[t * N_NODES + d] + a_k[t * N_NODES + s]) - m);
        }
#pragma unroll
        for (int off = 32; off > 0; off >>= 1) dsum += __shfl_xor(dsum, off);
        const float inv = 1.f / (dsum + 1e-16f);
        for (int i = beg; i < end; ++i) {
            unsigned p = sorted[i];
            int s = p & 0xffff, t = p >> 16;
            float alpha = __expf(lrelu(a_q[t * N_NODES + d] + a_k[t * N_NODES + s]) - m) * inv;
            float2 v = *(const float2*)(xw + ((size_t)t * N_NODES + s) * F_DIM + lane * 2);
            acc.x = fmaf(alpha, v.x, acc.x);
            acc.y = fmaf(alpha, v.y, acc.y);
        }
    }
    acc.x = fmaxf(acc.x, 0.f);
    acc.y = fmaxf(acc.y, 0.f);
    *(float2*)(out + (size_t)d * F_DIM + lane * 2) = acc;
}

// ---------------- driver ----------------

extern "C" void kernel_launch(void* const* d_in, const int* in_sizes, int n_in,
                              void* d_out, int out_size, void* d_ws, size_t ws_size,
                              hipStream_t stream) {
    const float* x     = (const float*)d_in[0];
    const float* W     = (const float*)d_in[1];
    const float* att_q = (const float*)d_in[2];
    const float* att_k = (const float*)d_in[3];
    const float* bias  = (const float*)d_in[4];
    const int* ei      = (const int*)d_in[5];
    const int* etp     = (const int*)d_in[6];
    const int* srcp = ei;
    const int* dstp = ei + N_EDGES;
    float* out = (float*)d_out;
    char* ws   = (char*)d_ws;

    size_t off = 0;
    auto alloc = [&](size_t bytes) {
        void* p = ws + off;
        off = (off + bytes + 511) & ~(size_t)511;
        return p;
    };
    float* xw        = (float*)alloc((size_t)N_REL * N_NODES * F_DIM * sizeof(float));
    float* a_q       = (float*)alloc((size_t)N_REL * N_NODES * sizeof(float));
    float* a_k       = (float*)alloc((size_t)N_REL * N_NODES * sizeof(float));
    int* cnt         = (int*)alloc((size_t)N_NODES * sizeof(int));
    int* row_ptr     = (int*)alloc(((size_t)N_NODES + 1) * sizeof(int));
    int* partial     = (int*)alloc(256 * sizeof(int));
    unsigned* sorted = (unsigned*)alloc((size_t)N_EDGES * sizeof(unsigned));
    short* Wh        = (short*)alloc((size_t)N_LAYERS * N_REL * F_DIM * F_DIM * sizeof(short));
    short* Wl        = (short*)alloc((size_t)N_LAYERS * N_REL * F_DIM * F_DIM * sizeof(short));

    // W split/transpose + CSR build (both layer-invariant)
    prep_w<<<N_LAYERS * N_REL, 256, 0, stream>>>(W, Wh, Wl);
    hipMemsetAsync(cnt, 0, (size_t)N_NODES * 4, stream);
    count_kernel<<<(N_EDGES + 255) / 256, 256, 0, stream>>>(dstp, cnt);
    block_sum_kernel<<<NBLK_N, 256, 0, stream>>>(cnt, partial);
    scan_partials_kernel<<<1, 256, 0, stream>>>(partial, row_ptr);
    scan_block_kernel<<<NBLK_N, 256, 0, stream>>>(cnt, partial, row_ptr);
    hipMemsetAsync(cnt, 0, (size_t)N_NODES * 4, stream);
    scatter_kernel<<<(N_EDGES + 255) / 256, 256, 0, stream>>>(
        srcp, dstp, etp, row_ptr, cnt, sorted);

    const int grid_m = (N_NODES + BM - 1) / BM;  // 782
    for (int l = 0; l < N_LAYERS; ++l) {
        const float* H = (l == 0) ? x : out;
        gemm_xw<<<grid_m, 256, 0, stream>>>(
            H, Wh + (size_t)l * N_REL * F_DIM * F_DIM,
            Wl + (size_t)l * N_REL * F_DIM * F_DIM,
            att_q + l * F_DIM, att_k + l * F_DIM, xw, a_q, a_k);
        agg_fused<<<(N_NODES + 3) / 4, 256, 0, stream>>>(
            xw, a_q, a_k, row_ptr, sorted, bias + l * F_DIM, out);
    }
}

// Round 4
// 670.949 us; speedup vs baseline: 1.1203x; 1.1203x over previous
//
#include <hip/hip_runtime.h>
#include <hip/hip_bf16.h>

#define N_NODES 50000
#define N_EDGES 500000
#define F_DIM   128
#define N_REL   8
#define N_LAYERS 2
#define NEG_SLOPE 0.2f

#define NBLK_N ((N_NODES + 255) / 256)   // 196 blocks over nodes

typedef short bf16x8 __attribute__((ext_vector_type(8)));
typedef float f32x4  __attribute__((ext_vector_type(4)));

// ---------------- helpers ----------------

__device__ inline short bfbits(float x) {
    __hip_bfloat16 h = __float2bfloat16(x);
    return *reinterpret_cast<short*>(&h);
}
__device__ inline float bf2f(short s) {
    unsigned u = ((unsigned)(unsigned short)s) << 16;
    return __uint_as_float(u);
}
__device__ inline float lrelu(float l) { return (l > 0.f) ? l : NEG_SLOPE * l; }

// ---------------- W prep: W[l,r,f,g] fp32 -> Wh/Wl[l,r,g,f] bf16 split -------
__global__ __launch_bounds__(256) void prep_w(const float* __restrict__ W,
                                              short* __restrict__ Wh,
                                              short* __restrict__ Wl) {
    __shared__ float tile[64][F_DIM + 1];
    const int mat = blockIdx.x;                      // l*N_REL + r
    const float* src = W + (size_t)mat * F_DIM * F_DIM;
    const int t = threadIdx.x;
    for (int hf = 0; hf < 2; ++hf) {
#pragma unroll
        for (int i = 0; i < 8; ++i) {
            int idx = t + i * 256;
            int f = idx >> 5, c4 = idx & 31;
            float4 v = *(const float4*)(src + (size_t)(hf * 64 + f) * F_DIM + c4 * 4);
            *(float4*)&tile[f][c4 * 4] = v;
        }
        __syncthreads();
        int g = t >> 1, fs = (t & 1) * 32;
        for (int c = 0; c < 4; ++c) {
            short th[8], tl[8];
#pragma unroll
            for (int j = 0; j < 8; ++j) {
                float x = tile[fs + c * 8 + j][g];
                short hb = bfbits(x);
                th[j] = hb;
                tl[j] = bfbits(x - bf2f(hb));
            }
            size_t o = ((size_t)mat * F_DIM + g) * F_DIM + hf * 64 + fs + c * 8;
            *(uint4*)(Wh + o) = *(const uint4*)th;
            *(uint4*)(Wl + o) = *(const uint4*)tl;
        }
        __syncthreads();
    }
}

// ---------------- MFMA GEMM (+fused q/k dots) ----------------
// grid (782, 8): blockIdx.x = 64-row tile, blockIdx.y = relation.
// 4 waves; wave w handles rows m0 + w*16 .. +15. No LDS, no barriers:
// A-fragments loaded directly from L2-resident H in MFMA layout.
#define BM 64
__global__ __launch_bounds__(256, 4) void gemm_xw(const float* __restrict__ H,
                                                  const short* __restrict__ Wh,
                                                  const short* __restrict__ Wl,
                                                  const float* __restrict__ qv_g,
                                                  const float* __restrict__ kv_g,
                                                  float* __restrict__ xw,
                                                  float* __restrict__ a_q,
                                                  float* __restrict__ a_k) {
    const int r   = blockIdx.y;
    const int m0  = blockIdx.x * BM;
    const int tid = threadIdx.x;
    const int lane = tid & 63, w = tid >> 6;
    const int q = lane >> 4, ln = lane & 15;

    const int grow = m0 + w * 16 + ln;                 // this lane's A row
    const int arow = (grow < N_NODES) ? grow : (N_NODES - 1);

    // A fragments (split hi/lo): A[m=ln][k=q*8+j], k-step ks covers ks*32..+31
    bf16x8 Ah[4], Al[4];
#pragma unroll
    for (int ks = 0; ks < 4; ++ks) {
        float av[8];
        *(float4*)(av)     = *(const float4*)(H + (size_t)arow * F_DIM + ks * 32 + q * 8);
        *(float4*)(av + 4) = *(const float4*)(H + (size_t)arow * F_DIM + ks * 32 + q * 8 + 4);
        bf16x8 h, l;
#pragma unroll
        for (int j = 0; j < 8; ++j) {
            short hb = bfbits(av[j]);
            h[j] = hb;
            l[j] = bfbits(av[j] - bf2f(hb));
        }
        Ah[ks] = h; Al[ks] = l;
    }

    f32x4 acc[8];
#pragma unroll
    for (int nf = 0; nf < 8; ++nf) acc[nf] = (f32x4)(0.f);

    const short* wh = Wh + (size_t)r * F_DIM * F_DIM;
    const short* wl = Wl + (size_t)r * F_DIM * F_DIM;
#pragma unroll
    for (int ks = 0; ks < 4; ++ks) {
#pragma unroll
        for (int nf = 0; nf < 8; ++nf) {
            size_t bo = (size_t)(nf * 16 + ln) * F_DIM + ks * 32 + q * 8;
            bf16x8 Bh = *(const bf16x8*)(wh + bo);
            bf16x8 Bl = *(const bf16x8*)(wl + bo);
            acc[nf] = __builtin_amdgcn_mfma_f32_16x16x32_bf16(Ah[ks], Bh, acc[nf], 0, 0, 0);
            acc[nf] = __builtin_amdgcn_mfma_f32_16x16x32_bf16(Ah[ks], Bl, acc[nf], 0, 0, 0);
            acc[nf] = __builtin_amdgcn_mfma_f32_16x16x32_bf16(Al[ks], Bh, acc[nf], 0, 0, 0);
        }
    }

    // q/k attention vector elements for this lane's columns
    float qvl[8], kvl[8];
#pragma unroll
    for (int nf = 0; nf < 8; ++nf) {
        qvl[nf] = qv_g[nf * 16 + ln];
        kvl[nf] = kv_g[nf * 16 + ln];
    }

    const int rowg = m0 + w * 16 + q * 4;   // base of this lane's 4 C-rows
    float pq[4] = {0, 0, 0, 0}, pk[4] = {0, 0, 0, 0};
#pragma unroll
    for (int nf = 0; nf < 8; ++nf) {
#pragma unroll
        for (int r4 = 0; r4 < 4; ++r4) {
            int row = rowg + r4;
            if (row < N_NODES)
                xw[((size_t)r * N_NODES + row) * F_DIM + nf * 16 + ln] = acc[nf][r4];
            pq[r4] = fmaf(acc[nf][r4], qvl[nf], pq[r4]);
            pk[r4] = fmaf(acc[nf][r4], kvl[nf], pk[r4]);
        }
    }
#pragma unroll
    for (int r4 = 0; r4 < 4; ++r4) {
#pragma unroll
        for (int m = 1; m <= 8; m <<= 1) {
            pq[r4] += __shfl_xor(pq[r4], m);
            pk[r4] += __shfl_xor(pk[r4], m);
        }
        int row = rowg + r4;
        if (ln == 0 && row < N_NODES) {
            a_q[(size_t)r * N_NODES + row] = pq[r4];
            a_k[(size_t)r * N_NODES + row] = pk[r4];
        }
    }
}

// ---------------- CSR build ----------------

__global__ __launch_bounds__(256) void count_kernel(const int* __restrict__ dstp,
                                                    int* __restrict__ cnt) {
    int e = blockIdx.x * 256 + threadIdx.x;
    if (e < N_EDGES) atomicAdd(cnt + dstp[e], 1);
}

__global__ __launch_bounds__(256) void block_sum_kernel(const int* __restrict__ cnt,
                                                        int* __restrict__ partial) {
    __shared__ int s[256];
    int idx = blockIdx.x * 256 + threadIdx.x;
    int v = (idx < N_NODES) ? cnt[idx] : 0;
    s[threadIdx.x] = v;
    __syncthreads();
    for (int off = 128; off > 0; off >>= 1) {
        if (threadIdx.x < off) s[threadIdx.x] += s[threadIdx.x + off];
        __syncthreads();
    }
    if (threadIdx.x == 0) partial[blockIdx.x] = s[0];
}

__global__ __launch_bounds__(256) void scan_partials_kernel(int* __restrict__ partial,
                                                            int* __restrict__ row_ptr) {
    __shared__ int s[256];
    int t = threadIdx.x;
    int v = (t < NBLK_N) ? partial[t] : 0;
    s[t] = v;
    __syncthreads();
#pragma unroll
    for (int off = 1; off < 256; off <<= 1) {
        int x = (t >= off) ? s[t - off] : 0;
        __syncthreads();
        s[t] += x;
        __syncthreads();
    }
    if (t < NBLK_N) partial[t] = s[t] - v;
    if (t == 0) row_ptr[N_NODES] = N_EDGES;
}

__global__ __launch_bounds__(256) void scan_block_kernel(const int* __restrict__ cnt,
                                                         const int* __restrict__ partial,
                                                         int* __restrict__ row_ptr) {
    __shared__ int s[256];
    int t = threadIdx.x;
    int idx = blockIdx.x * 256 + t;
    int v = (idx < N_NODES) ? cnt[idx] : 0;
    s[t] = v;
    __syncthreads();
#pragma unroll
    for (int off = 1; off < 256; off <<= 1) {
        int x = (t >= off) ? s[t - off] : 0;
        __syncthreads();
        s[t] += x;
        __syncthreads();
    }
    if (idx < N_NODES) row_ptr[idx] = partial[blockIdx.x] + s[t] - v;
}

__global__ __launch_bounds__(256) void scatter_kernel(const int* __restrict__ srcp,
                                                      const int* __restrict__ dstp,
                                                      const int* __restrict__ etp,
                                                      const int* __restrict__ row_ptr,
                                                      int* __restrict__ cursor,
                                                      unsigned* __restrict__ sorted) {
    int e = blockIdx.x * 256 + threadIdx.x;
    if (e >= N_EDGES) return;
    int d = dstp[e];
    int pos = atomicAdd(cursor + d, 1);
    sorted[row_ptr[d] + pos] = (unsigned)srcp[e] | ((unsigned)etp[e] << 16);
}

// ---------------- fused softmax + aggregate + bias + relu ----------------
__global__ __launch_bounds__(256) void agg_fused(const float* __restrict__ xw,
                                                 const float* __restrict__ a_q,
                                                 const float* __restrict__ a_k,
                                                 const int* __restrict__ row_ptr,
                                                 const unsigned* __restrict__ sorted,
                                                 const float* __restrict__ bias,
                                                 float* __restrict__ out) {
    const int lane = threadIdx.x & 63;
    const int wave = threadIdx.x >> 6;
    const int d = blockIdx.x * 4 + wave;
    if (d >= N_NODES) return;
    const int beg = row_ptr[d], end = row_ptr[d + 1];
    const int cnt = end - beg;

    float2 acc = *(const float2*)(bias + lane * 2);

    if (cnt <= 64) {
        unsigned p = 0;
        float l = -3.4e38f;
        if (lane < cnt) {
            p = sorted[beg + lane];
            int s = p & 0xffff, t = p >> 16;
            l = lrelu(a_q[t * N_NODES + d] + a_k[t * N_NODES + s]);
        }
        float m = l;
#pragma unroll
        for (int off = 32; off > 0; off >>= 1) m = fmaxf(m, __shfl_xor(m, off));
        float ex = (lane < cnt) ? __expf(l - m) : 0.f;
        float dsum = ex;
#pragma unroll
        for (int off = 32; off > 0; off >>= 1) dsum += __shfl_xor(dsum, off);
        float alpha = ex / (dsum + 1e-16f);

        int i = 0;
        for (; i + 4 <= cnt; i += 4) {
            unsigned p0 = __shfl(p, i), p1 = __shfl(p, i + 1);
            unsigned p2 = __shfl(p, i + 2), p3 = __shfl(p, i + 3);
            float a0 = __shfl(alpha, i), a1 = __shfl(alpha, i + 1);
            float a2 = __shfl(alpha, i + 2), a3 = __shfl(alpha, i + 3);
            float2 v0 = *(const float2*)(xw + (((size_t)(p0 >> 16)) * N_NODES + (p0 & 0xffff)) * F_DIM + lane * 2);
            float2 v1 = *(const float2*)(xw + (((size_t)(p1 >> 16)) * N_NODES + (p1 & 0xffff)) * F_DIM + lane * 2);
            float2 v2 = *(const float2*)(xw + (((size_t)(p2 >> 16)) * N_NODES + (p2 & 0xffff)) * F_DIM + lane * 2);
            float2 v3 = *(const float2*)(xw + (((size_t)(p3 >> 16)) * N_NODES + (p3 & 0xffff)) * F_DIM + lane * 2);
            acc.x = fmaf(a0, v0.x, acc.x); acc.y = fmaf(a0, v0.y, acc.y);
            acc.x = fmaf(a1, v1.x, acc.x); acc.y = fmaf(a1, v1.y, acc.y);
            acc.x = fmaf(a2, v2.x, acc.x); acc.y = fmaf(a2, v2.y, acc.y);
            acc.x = fmaf(a3, v3.x, acc.x); acc.y = fmaf(a3, v3.y, acc.y);
        }
        for (; i < cnt; ++i) {
            unsigned pi = __shfl(p, i);
            float ai = __shfl(alpha, i);
            float2 v = *(const float2*)(xw + (((size_t)(pi >> 16)) * N_NODES + (pi & 0xffff)) * F_DIM + lane * 2);
            acc.x = fmaf(ai, v.x, acc.x);
            acc.y = fmaf(ai, v.y, acc.y);
        }
    } else {
        float m = -3.4e38f;
        for (int i = beg + lane; i < end; i += 64) {
            unsigned p = sorted[i];
            int s = p & 0xffff, t = p >> 16;
            m = fmaxf(m, lrelu(a_q[t * N_NODES + d] + a_k[t * N_NODES + s]));
        }
#pragma unroll
        for (int off = 32; off > 0; off >>= 1) m = fmaxf(m, __shfl_xor(m, off));
        float dsum = 0.f;
        for (int i = beg + lane; i < end; i += 64) {
            unsigned p = sorted[i];
            int s = p & 0xffff, t = p >> 16;
            dsum += __expf(lrelu(a_q[t * N_NODES + d] + a_k[t * N_NODES + s]) - m);
        }
#pragma unroll
        for (int off = 32; off > 0; off >>= 1) dsum += __shfl_xor(dsum, off);
        const float inv = 1.f / (dsum + 1e-16f);
        for (int i = beg; i < end; ++i) {
            unsigned p = sorted[i];
            int s = p & 0xffff, t = p >> 16;
            float alpha = __expf(lrelu(a_q[t * N_NODES + d] + a_k[t * N_NODES + s]) - m) * inv;
            float2 v = *(const float2*)(xw + ((size_t)t * N_NODES + s) * F_DIM + lane * 2);
            acc.x = fmaf(alpha, v.x, acc.x);
            acc.y = fmaf(alpha, v.y, acc.y);
        }
    }
    acc.x = fmaxf(acc.x, 0.f);
    acc.y = fmaxf(acc.y, 0.f);
    *(float2*)(out + (size_t)d * F_DIM + lane * 2) = acc;
}

// ---------------- driver ----------------

extern "C" void kernel_launch(void* const* d_in, const int* in_sizes, int n_in,
                              void* d_out, int out_size, void* d_ws, size_t ws_size,
                              hipStream_t stream) {
    const float* x     = (const float*)d_in[0];
    const float* W     = (const float*)d_in[1];
    const float* att_q = (const float*)d_in[2];
    const float* att_k = (const float*)d_in[3];
    const float* bias  = (const float*)d_in[4];
    const int* ei      = (const int*)d_in[5];
    const int* etp     = (const int*)d_in[6];
    const int* srcp = ei;
    const int* dstp = ei + N_EDGES;
    float* out = (float*)d_out;
    char* ws   = (char*)d_ws;

    size_t off = 0;
    auto alloc = [&](size_t bytes) {
        void* p = ws + off;
        off = (off + bytes + 511) & ~(size_t)511;
        return p;
    };
    float* xw        = (float*)alloc((size_t)N_REL * N_NODES * F_DIM * sizeof(float));
    float* a_q       = (float*)alloc((size_t)N_REL * N_NODES * sizeof(float));
    float* a_k       = (float*)alloc((size_t)N_REL * N_NODES * sizeof(float));
    int* cnt         = (int*)alloc((size_t)N_NODES * sizeof(int));
    int* row_ptr     = (int*)alloc(((size_t)N_NODES + 1) * sizeof(int));
    int* partial     = (int*)alloc(256 * sizeof(int));
    unsigned* sorted = (unsigned*)alloc((size_t)N_EDGES * sizeof(unsigned));
    short* Wh        = (short*)alloc((size_t)N_LAYERS * N_REL * F_DIM * F_DIM * sizeof(short));
    short* Wl        = (short*)alloc((size_t)N_LAYERS * N_REL * F_DIM * F_DIM * sizeof(short));

    prep_w<<<N_LAYERS * N_REL, 256, 0, stream>>>(W, Wh, Wl);
    hipMemsetAsync(cnt, 0, (size_t)N_NODES * 4, stream);
    count_kernel<<<(N_EDGES + 255) / 256, 256, 0, stream>>>(dstp, cnt);
    block_sum_kernel<<<NBLK_N, 256, 0, stream>>>(cnt, partial);
    scan_partials_kernel<<<1, 256, 0, stream>>>(partial, row_ptr);
    scan_block_kernel<<<NBLK_N, 256, 0, stream>>>(cnt, partial, row_ptr);
    hipMemsetAsync(cnt, 0, (size_t)N_NODES * 4, stream);
    scatter_kernel<<<(N_EDGES + 255) / 256, 256, 0, stream>>>(
        srcp, dstp, etp, row_ptr, cnt, sorted);

    const int grid_m = (N_NODES + BM - 1) / BM;  // 782
    for (int l = 0; l < N_LAYERS; ++l) {
        const float* H = (l == 0) ? x : out;
        gemm_xw<<<dim3(grid_m, N_REL), 256, 0, stream>>>(
            H, Wh + (size_t)l * N_REL * F_DIM * F_DIM,
            Wl + (size_t)l * N_REL * F_DIM * F_DIM,
            att_q + l * F_DIM, att_k + l * F_DIM, xw, a_q, a_k);
        agg_fused<<<(N_NODES + 3) / 4, 256, 0, stream>>>(
            xw, a_q, a_k, row_ptr, sorted, bias + l * F_DIM, out);
    }
}

// Round 5
// 587.363 us; speedup vs baseline: 1.2797x; 1.1423x over previous
//
#include <hip/hip_runtime.h>
#include <hip/hip_bf16.h>
#include <hip/hip_fp16.h>

#define N_NODES 50000
#define N_EDGES 500000
#define F_DIM   128
#define N_REL   8
#define N_LAYERS 2
#define NEG_SLOPE 0.2f

#define NBLK_N ((N_NODES + 255) / 256)   // 196 blocks over nodes

typedef short bf16x8 __attribute__((ext_vector_type(8)));
typedef float f32x4  __attribute__((ext_vector_type(4)));

// ---------------- helpers ----------------

__device__ inline short bfbits(float x) {
    __hip_bfloat16 h = __float2bfloat16(x);
    return *reinterpret_cast<short*>(&h);
}
__device__ inline float bf2f(short s) {
    unsigned u = ((unsigned)(unsigned short)s) << 16;
    return __uint_as_float(u);
}
__device__ inline float lrelu(float l) { return (l > 0.f) ? l : NEG_SLOPE * l; }

// ---------------- W prep: W[l,r,f,g] fp32 -> Wh/Wl[l,r,g,f] bf16 split -------
__global__ __launch_bounds__(256) void prep_w(const float* __restrict__ W,
                                              short* __restrict__ Wh,
                                              short* __restrict__ Wl) {
    __shared__ float tile[64][F_DIM + 1];
    const int mat = blockIdx.x;                      // l*N_REL + r
    const float* src = W + (size_t)mat * F_DIM * F_DIM;
    const int t = threadIdx.x;
    for (int hf = 0; hf < 2; ++hf) {
#pragma unroll
        for (int i = 0; i < 8; ++i) {
            int idx = t + i * 256;
            int f = idx >> 5, c4 = idx & 31;
            float4 v = *(const float4*)(src + (size_t)(hf * 64 + f) * F_DIM + c4 * 4);
            *(float4*)&tile[f][c4 * 4] = v;
        }
        __syncthreads();
        int g = t >> 1, fs = (t & 1) * 32;
        for (int c = 0; c < 4; ++c) {
            short th[8], tl[8];
#pragma unroll
            for (int j = 0; j < 8; ++j) {
                float x = tile[fs + c * 8 + j][g];
                short hb = bfbits(x);
                th[j] = hb;
                tl[j] = bfbits(x - bf2f(hb));
            }
            size_t o = ((size_t)mat * F_DIM + g) * F_DIM + hf * 64 + fs + c * 8;
            *(uint4*)(Wh + o) = *(const uint4*)th;
            *(uint4*)(Wl + o) = *(const uint4*)tl;
        }
        __syncthreads();
    }
}

// ---------------- wq[l,r,f] = sum_g W[l,r,f,g]*q[l,g]  (and wk) -------------
__global__ __launch_bounds__(128) void prep_qk(const float* __restrict__ W,
                                               const float* __restrict__ qa,
                                               const float* __restrict__ ka,
                                               float* __restrict__ wq,
                                               float* __restrict__ wk) {
    const int mat = blockIdx.x;          // l*N_REL + r
    const int l = mat >> 3;
    const int f = threadIdx.x;           // 128
    const float* w  = W + (size_t)mat * F_DIM * F_DIM + (size_t)f * F_DIM;
    const float* qv = qa + l * F_DIM;
    const float* kv = ka + l * F_DIM;
    float sq = 0.f, sk = 0.f;
#pragma unroll
    for (int g = 0; g < F_DIM; g += 4) {
        float4 wv = *(const float4*)(w + g);
        float4 q4 = *(const float4*)(qv + g);
        float4 k4 = *(const float4*)(kv + g);
        sq += wv.x * q4.x + wv.y * q4.y + wv.z * q4.z + wv.w * q4.w;
        sk += wv.x * k4.x + wv.y * k4.y + wv.z * k4.z + wv.w * k4.w;
    }
    wq[mat * F_DIM + f] = sq;
    wk[mat * F_DIM + f] = sk;
}

// ---------------- B-stationary MFMA GEMM ----------------
// grid (196, 8). Block: 256 rows of one relation. Wave w pins cols w*32..+31
// of split-W in registers (loaded once), streams 8 double-row-tiles (32 rows).
#define ROWS_PER_BLOCK 256
__global__ __launch_bounds__(256, 2) void gemm_xw(const float* __restrict__ H,
                                                  const short* __restrict__ Wh,
                                                  const short* __restrict__ Wl,
                                                  __half* __restrict__ xw) {
    const int r   = blockIdx.y;
    const int rb0 = blockIdx.x * ROWS_PER_BLOCK;
    const int tid = threadIdx.x;
    const int lane = tid & 63, w = tid >> 6;
    const int q = lane >> 4, ln = lane & 15;

    const short* wh = Wh + (size_t)r * F_DIM * F_DIM;
    const short* wl = Wl + (size_t)r * F_DIM * F_DIM;

    // stationary B: col-tile t covers cols (w*2+t)*16..+15
    bf16x8 Bh[2][4], Bl[2][4];
#pragma unroll
    for (int t = 0; t < 2; ++t)
#pragma unroll
        for (int ks = 0; ks < 4; ++ks) {
            size_t bo = (size_t)((w * 2 + t) * 16 + ln) * F_DIM + ks * 32 + q * 8;
            Bh[t][ks] = *(const bf16x8*)(wh + bo);
            Bl[t][ks] = *(const bf16x8*)(wl + bo);
        }

    for (int dt = 0; dt < ROWS_PER_BLOCK / 32; ++dt) {
        const int rb = rb0 + dt * 32;
        // A fragments for 2 row-tiles (rows rb+rt*16+ln), split hi/lo
        bf16x8 Ah[2][4], Al[2][4];
#pragma unroll
        for (int rt = 0; rt < 2; ++rt) {
            int row = rb + rt * 16 + ln;
            int ar = (row < N_NODES) ? row : (N_NODES - 1);
            const float* hp = H + (size_t)ar * F_DIM;
#pragma unroll
            for (int ks = 0; ks < 4; ++ks) {
                float av[8];
                *(float4*)(av)     = *(const float4*)(hp + ks * 32 + q * 8);
                *(float4*)(av + 4) = *(const float4*)(hp + ks * 32 + q * 8 + 4);
                bf16x8 h, l;
#pragma unroll
                for (int j = 0; j < 8; ++j) {
                    short hb = bfbits(av[j]);
                    h[j] = hb;
                    l[j] = bfbits(av[j] - bf2f(hb));
                }
                Ah[rt][ks] = h; Al[rt][ks] = l;
            }
        }

        f32x4 acc[4];   // c = rt*2 + t
#pragma unroll
        for (int c = 0; c < 4; ++c) acc[c] = (f32x4)(0.f);
#pragma unroll
        for (int ks = 0; ks < 4; ++ks) {
            // 4 independent chains per pass: no back-to-back dependent MFMAs
#pragma unroll
            for (int c = 0; c < 4; ++c)
                acc[c] = __builtin_amdgcn_mfma_f32_16x16x32_bf16(Ah[c >> 1][ks], Bh[c & 1][ks], acc[c], 0, 0, 0);
#pragma unroll
            for (int c = 0; c < 4; ++c)
                acc[c] = __builtin_amdgcn_mfma_f32_16x16x32_bf16(Ah[c >> 1][ks], Bl[c & 1][ks], acc[c], 0, 0, 0);
#pragma unroll
            for (int c = 0; c < 4; ++c)
                acc[c] = __builtin_amdgcn_mfma_f32_16x16x32_bf16(Al[c >> 1][ks], Bh[c & 1][ks], acc[c], 0, 0, 0);
        }

        // store fp16: row = rb + rt*16 + q*4 + reg, col = (w*2+t)*16 + ln
#pragma unroll
        for (int c = 0; c < 4; ++c) {
            const int rt = c >> 1, t = c & 1;
            const int col = (w * 2 + t) * 16 + ln;
#pragma unroll
            for (int reg = 0; reg < 4; ++reg) {
                int row = rb + rt * 16 + q * 4 + reg;
                if (row < N_NODES)
                    xw[((size_t)r * N_NODES + row) * F_DIM + col] = __float2half(acc[c][reg]);
            }
        }
    }
}

// ---------------- a_q[r,n] = h[n].wq[r] ; a_k likewise. one wave per node ----
__global__ __launch_bounds__(256) void qk_nodes(const float* __restrict__ H,
                                                const float* __restrict__ wq,
                                                const float* __restrict__ wk,
                                                float* __restrict__ a_q,
                                                float* __restrict__ a_k) {
    const int lane = threadIdx.x & 63;
    const int wave = threadIdx.x >> 6;
    const int n = blockIdx.x * 4 + wave;
    if (n >= N_NODES) return;
    float2 h2 = *(const float2*)(H + (size_t)n * F_DIM + lane * 2);
#pragma unroll
    for (int r = 0; r < N_REL; ++r) {
        float2 q2 = *(const float2*)(wq + r * F_DIM + lane * 2);
        float2 k2 = *(const float2*)(wk + r * F_DIM + lane * 2);
        float pq = h2.x * q2.x + h2.y * q2.y;
        float pk = h2.x * k2.x + h2.y * k2.y;
#pragma unroll
        for (int off = 32; off > 0; off >>= 1) {
            pq += __shfl_xor(pq, off);
            pk += __shfl_xor(pk, off);
        }
        if (lane == 0) {
            a_q[r * N_NODES + n] = pq;
            a_k[r * N_NODES + n] = pk;
        }
    }
}

// ---------------- CSR build ----------------

__global__ __launch_bounds__(256) void count_kernel(const int* __restrict__ dstp,
                                                    int* __restrict__ cnt) {
    int e = blockIdx.x * 256 + threadIdx.x;
    if (e < N_EDGES) atomicAdd(cnt + dstp[e], 1);
}

__global__ __launch_bounds__(256) void block_sum_kernel(const int* __restrict__ cnt,
                                                        int* __restrict__ partial) {
    __shared__ int s[256];
    int idx = blockIdx.x * 256 + threadIdx.x;
    int v = (idx < N_NODES) ? cnt[idx] : 0;
    s[threadIdx.x] = v;
    __syncthreads();
    for (int off = 128; off > 0; off >>= 1) {
        if (threadIdx.x < off) s[threadIdx.x] += s[threadIdx.x + off];
        __syncthreads();
    }
    if (threadIdx.x == 0) partial[blockIdx.x] = s[0];
}

__global__ __launch_bounds__(256) void scan_partials_kernel(int* __restrict__ partial,
                                                            int* __restrict__ row_ptr) {
    __shared__ int s[256];
    int t = threadIdx.x;
    int v = (t < NBLK_N) ? partial[t] : 0;
    s[t] = v;
    __syncthreads();
#pragma unroll
    for (int off = 1; off < 256; off <<= 1) {
        int x = (t >= off) ? s[t - off] : 0;
        __syncthreads();
        s[t] += x;
        __syncthreads();
    }
    if (t < NBLK_N) partial[t] = s[t] - v;
    if (t == 0) row_ptr[N_NODES] = N_EDGES;
}

__global__ __launch_bounds__(256) void scan_block_kernel(const int* __restrict__ cnt,
                                                         const int* __restrict__ partial,
                                                         int* __restrict__ row_ptr) {
    __shared__ int s[256];
    int t = threadIdx.x;
    int idx = blockIdx.x * 256 + t;
    int v = (idx < N_NODES) ? cnt[idx] : 0;
    s[t] = v;
    __syncthreads();
#pragma unroll
    for (int off = 1; off < 256; off <<= 1) {
        int x = (t >= off) ? s[t - off] : 0;
        __syncthreads();
        s[t] += x;
        __syncthreads();
    }
    if (idx < N_NODES) row_ptr[idx] = partial[blockIdx.x] + s[t] - v;
}

__global__ __launch_bounds__(256) void scatter_kernel(const int* __restrict__ srcp,
                                                      const int* __restrict__ dstp,
                                                      const int* __restrict__ etp,
                                                      const int* __restrict__ row_ptr,
                                                      int* __restrict__ cursor,
                                                      unsigned* __restrict__ sorted) {
    int e = blockIdx.x * 256 + threadIdx.x;
    if (e >= N_EDGES) return;
    int d = dstp[e];
    int pos = atomicAdd(cursor + d, 1);
    sorted[row_ptr[d] + pos] = (unsigned)srcp[e] | ((unsigned)etp[e] << 16);
}

// ---------------- fused softmax + aggregate + bias + relu ----------------
__device__ inline float2 ldxw(const __half* xw, unsigned p, int lane) {
    const __half2 h2 = *((const __half2*)xw + (((size_t)(p >> 16)) * N_NODES + (p & 0xffff)) * (F_DIM / 2) + lane);
    return make_float2(__half2float(h2.x), __half2float(h2.y));
}

__global__ __launch_bounds__(256) void agg_fused(const __half* __restrict__ xw,
                                                 const float* __restrict__ a_q,
                                                 const float* __restrict__ a_k,
                                                 const int* __restrict__ row_ptr,
                                                 const unsigned* __restrict__ sorted,
                                                 const float* __restrict__ bias,
                                                 float* __restrict__ out) {
    const int lane = threadIdx.x & 63;
    const int wave = threadIdx.x >> 6;
    const int d = blockIdx.x * 4 + wave;
    if (d >= N_NODES) return;
    const int beg = row_ptr[d], end = row_ptr[d + 1];
    const int cnt = end - beg;

    float2 acc = *(const float2*)(bias + lane * 2);

    if (cnt <= 64) {
        unsigned p = 0;
        float l = -3.4e38f;
        if (lane < cnt) {
            p = sorted[beg + lane];
            int s = p & 0xffff, t = p >> 16;
            l = lrelu(a_q[t * N_NODES + d] + a_k[t * N_NODES + s]);
        }
        float m = l;
#pragma unroll
        for (int off = 32; off > 0; off >>= 1) m = fmaxf(m, __shfl_xor(m, off));
        float ex = (lane < cnt) ? __expf(l - m) : 0.f;
        float dsum = ex;
#pragma unroll
        for (int off = 32; off > 0; off >>= 1) dsum += __shfl_xor(dsum, off);
        float alpha = ex / (dsum + 1e-16f);

        int i = 0;
        for (; i + 4 <= cnt; i += 4) {
            unsigned p0 = __shfl(p, i), p1 = __shfl(p, i + 1);
            unsigned p2 = __shfl(p, i + 2), p3 = __shfl(p, i + 3);
            float a0 = __shfl(alpha, i), a1 = __shfl(alpha, i + 1);
            float a2 = __shfl(alpha, i + 2), a3 = __shfl(alpha, i + 3);
            float2 v0 = ldxw(xw, p0, lane);
            float2 v1 = ldxw(xw, p1, lane);
            float2 v2 = ldxw(xw, p2, lane);
            float2 v3 = ldxw(xw, p3, lane);
            acc.x = fmaf(a0, v0.x, acc.x); acc.y = fmaf(a0, v0.y, acc.y);
            acc.x = fmaf(a1, v1.x, acc.x); acc.y = fmaf(a1, v1.y, acc.y);
            acc.x = fmaf(a2, v2.x, acc.x); acc.y = fmaf(a2, v2.y, acc.y);
            acc.x = fmaf(a3, v3.x, acc.x); acc.y = fmaf(a3, v3.y, acc.y);
        }
        for (; i < cnt; ++i) {
            unsigned pi = __shfl(p, i);
            float ai = __shfl(alpha, i);
            float2 v = ldxw(xw, pi, lane);
            acc.x = fmaf(ai, v.x, acc.x);
            acc.y = fmaf(ai, v.y, acc.y);
        }
    } else {
        float m = -3.4e38f;
        for (int i = beg + lane; i < end; i += 64) {
            unsigned p = sorted[i];
            int s = p & 0xffff, t = p >> 16;
            m = fmaxf(m, lrelu(a_q[t * N_NODES + d] + a_k[t * N_NODES + s]));
        }
#pragma unroll
        for (int off = 32; off > 0; off >>= 1) m = fmaxf(m, __shfl_xor(m, off));
        float dsum = 0.f;
        for (int i = beg + lane; i < end; i += 64) {
            unsigned p = sorted[i];
            int s = p & 0xffff, t = p >> 16;
            dsum += __expf(lrelu(a_q[t * N_NODES + d] + a_k[t * N_NODES + s]) - m);
        }
#pragma unroll
        for (int off = 32; off > 0; off >>= 1) dsum += __shfl_xor(dsum, off);
        const float inv = 1.f / (dsum + 1e-16f);
        for (int i = beg; i < end; ++i) {
            unsigned p = sorted[i];
            int s = p & 0xffff, t = p >> 16;
            float alpha = __expf(lrelu(a_q[t * N_NODES + d] + a_k[t * N_NODES + s]) - m) * inv;
            float2 v = ldxw(xw, p, lane);
            acc.x = fmaf(alpha, v.x, acc.x);
            acc.y = fmaf(alpha, v.y, acc.y);
        }
    }
    acc.x = fmaxf(acc.x, 0.f);
    acc.y = fmaxf(acc.y, 0.f);
    *(float2*)(out + (size_t)d * F_DIM + lane * 2) = acc;
}

// ---------------- driver ----------------

extern "C" void kernel_launch(void* const* d_in, const int* in_sizes, int n_in,
                              void* d_out, int out_size, void* d_ws, size_t ws_size,
                              hipStream_t stream) {
    const float* x     = (const float*)d_in[0];
    const float* W     = (const float*)d_in[1];
    const float* att_q = (const float*)d_in[2];
    const float* att_k = (const float*)d_in[3];
    const float* bias  = (const float*)d_in[4];
    const int* ei      = (const int*)d_in[5];
    const int* etp     = (const int*)d_in[6];
    const int* srcp = ei;
    const int* dstp = ei + N_EDGES;
    float* out = (float*)d_out;
    char* ws   = (char*)d_ws;

    size_t off = 0;
    auto alloc = [&](size_t bytes) {
        void* p = ws + off;
        off = (off + bytes + 511) & ~(size_t)511;
        return p;
    };
    __half* xw       = (__half*)alloc((size_t)N_REL * N_NODES * F_DIM * sizeof(__half));
    float* a_q       = (float*)alloc((size_t)N_REL * N_NODES * sizeof(float));
    float* a_k       = (float*)alloc((size_t)N_REL * N_NODES * sizeof(float));
    int* cnt         = (int*)alloc((size_t)N_NODES * sizeof(int));
    int* row_ptr     = (int*)alloc(((size_t)N_NODES + 1) * sizeof(int));
    int* partial     = (int*)alloc(256 * sizeof(int));
    unsigned* sorted = (unsigned*)alloc((size_t)N_EDGES * sizeof(unsigned));
    short* Wh        = (short*)alloc((size_t)N_LAYERS * N_REL * F_DIM * F_DIM * sizeof(short));
    short* Wl        = (short*)alloc((size_t)N_LAYERS * N_REL * F_DIM * F_DIM * sizeof(short));
    float* wq        = (float*)alloc((size_t)N_LAYERS * N_REL * F_DIM * sizeof(float));
    float* wk        = (float*)alloc((size_t)N_LAYERS * N_REL * F_DIM * sizeof(float));

    prep_w<<<N_LAYERS * N_REL, 256, 0, stream>>>(W, Wh, Wl);
    prep_qk<<<N_LAYERS * N_REL, 128, 0, stream>>>(W, att_q, att_k, wq, wk);
    hipMemsetAsync(cnt, 0, (size_t)N_NODES * 4, stream);
    count_kernel<<<(N_EDGES + 255) / 256, 256, 0, stream>>>(dstp, cnt);
    block_sum_kernel<<<NBLK_N, 256, 0, stream>>>(cnt, partial);
    scan_partials_kernel<<<1, 256, 0, stream>>>(partial, row_ptr);
    scan_block_kernel<<<NBLK_N, 256, 0, stream>>>(cnt, partial, row_ptr);
    hipMemsetAsync(cnt, 0, (size_t)N_NODES * 4, stream);
    scatter_kernel<<<(N_EDGES + 255) / 256, 256, 0, stream>>>(
        srcp, dstp, etp, row_ptr, cnt, sorted);

    const int grid_m = (N_NODES + ROWS_PER_BLOCK - 1) / ROWS_PER_BLOCK;  // 196
    for (int l = 0; l < N_LAYERS; ++l) {
        const float* H = (l == 0) ? x : out;
        gemm_xw<<<dim3(grid_m, N_REL), 256, 0, stream>>>(
            H, Wh + (size_t)l * N_REL * F_DIM * F_DIM,
            Wl + (size_t)l * N_REL * F_DIM * F_DIM, xw);
        qk_nodes<<<(N_NODES + 3) / 4, 256, 0, stream>>>(
            H, wq + (size_t)l * N_REL * F_DIM, wk + (size_t)l * N_REL * F_DIM, a_q, a_k);
        agg_fused<<<(N_NODES + 3) / 4, 256, 0, stream>>>(
            xw, a_q, a_k, row_ptr, sorted, bias + l * F_DIM, out);
    }
}